// Round 1
// baseline (939.499 us; speedup 1.0000x reference)
//
#include <hip/hip_runtime.h>
#include <hip/hip_bf16.h>
#include <cstdint>
#include <cstddef>

typedef int v4i __attribute__((ext_vector_type(4)));

#define NH 32
#define HD 128
#define SEQ 1024
#define HID 4096
#define BB 2

__device__ __forceinline__ signed char quant_i8(float x) {
    float r = rintf(x);                       // round-half-to-even, matches jnp.round
    r = fminf(fmaxf(r, -128.0f), 127.0f);
    return (signed char)r;
}

// ---------------- pack int32 -> int8 ----------------
__global__ __launch_bounds__(256) void pack_i8_kernel(const int* __restrict__ src,
                                                      signed char* __restrict__ dst, int n4) {
    int i = blockIdx.x * 256 + threadIdx.x;
    if (i >= n4) return;
    int4 v = ((const int4*)src)[i];
    char4 c;
    c.x = (signed char)v.x; c.y = (signed char)v.y;
    c.z = (signed char)v.z; c.w = (signed char)v.w;
    ((char4*)dst)[i] = c;
}

// ---------------- quantize hidden_states ----------------
__global__ __launch_bounds__(256) void quant_x_kernel(const float* __restrict__ src,
                                                      signed char* __restrict__ dst, int n4) {
    int i = blockIdx.x * 256 + threadIdx.x;
    if (i >= n4) return;
    float4 v = ((const float4*)src)[i];
    char4 c;
    c.x = quant_i8(v.x * 50.0f);
    c.y = quant_i8(v.y * 50.0f);
    c.z = quant_i8(v.z * 50.0f);
    c.w = quant_i8(v.w * 50.0f);
    ((char4*)dst)[i] = c;
}

// ---------------- int8 GEMM: C[m,n] = sum_k A[m,k]*B[n,k] ----------------
// 128x128 block tile, 4 waves each 64x64, mfma_i32_16x16x64_i8.
template<bool F32OUT>
__global__ __launch_bounds__(256) void gemm_i8_kernel(
    const signed char* __restrict__ A, const signed char* __restrict__ Bw,
    const void* __restrict__ bias, void* __restrict__ outp,
    int M, int N, int K, float alpha, float beta)
{
    const int w    = threadIdx.x >> 6;
    const int lane = threadIdx.x & 63;
    const int m0   = blockIdx.y * 128 + (w >> 1) * 64;
    const int n0   = blockIdx.x * 128 + (w & 1) * 64;
    const int lm   = lane & 15;
    const int lkb  = (lane >> 4) * 16;

    v4i acc[4][4] = {};

    const signed char* ap = A  + (size_t)(m0 + lm) * K + lkb;
    const signed char* bp = Bw + (size_t)(n0 + lm) * K + lkb;

    for (int k0 = 0; k0 < K; k0 += 64) {
        v4i af[4], bf[4];
        #pragma unroll
        for (int i = 0; i < 4; i++)
            af[i] = *(const v4i*)(ap + (size_t)(16 * i) * K + k0);
        #pragma unroll
        for (int j = 0; j < 4; j++)
            bf[j] = *(const v4i*)(bp + (size_t)(16 * j) * K + k0);
        #pragma unroll
        for (int i = 0; i < 4; i++)
            #pragma unroll
            for (int j = 0; j < 4; j++)
                acc[i][j] = __builtin_amdgcn_mfma_i32_16x16x64_i8(af[i], bf[j], acc[i][j], 0, 0, 0);
    }

    const int orow = (lane >> 4) * 4;
    #pragma unroll
    for (int i = 0; i < 4; i++) {
        #pragma unroll
        for (int j = 0; j < 4; j++) {
            #pragma unroll
            for (int r = 0; r < 4; r++) {
                int row = m0 + 16 * i + orow + r;
                int col = n0 + 16 * j + lm;
                float v = (float)acc[i][j][r];
                if (F32OUT) {
                    ((float*)outp)[(size_t)row * N + col] = v * alpha + ((const float*)bias)[col];
                } else {
                    float q = v * alpha + (float)((const int*)bias)[col] * beta;
                    ((signed char*)outp)[(size_t)row * N + col] = quant_i8(q);
                }
            }
        }
    }
}

// ---------------- RoPE (in-place on q,k) + V transpose ----------------
__global__ __launch_bounds__(128) void rope_kernel(
    const int* __restrict__ pos_ids, signed char* __restrict__ q,
    signed char* __restrict__ k, const signed char* __restrict__ v,
    signed char* __restrict__ vt)
{
    int bid = blockIdx.x;
    int h = bid & (NH - 1);
    int s = (bid >> 5) & (SEQ - 1);
    int b = bid >> 15;
    int d = threadIdx.x;
    size_t base = ((size_t)(b * SEQ + s) * NH + h) * (size_t)HD;
    int pos = pos_ids[b * SEQ + s];

    // inv_freq = 10000^(-2*(d&63)/128)
    float inv = expf(-(float)(2 * (d & 63)) * (9.210340371976184f / 128.0f));
    float freq = (float)pos * inv;
    float cs = cosf(freq), sn = sinf(freq);

    float qd = (float)q[base + d];
    float qp = (float)q[base + (d ^ 64)];
    float kd = (float)k[base + d];
    float kp = (float)k[base + (d ^ 64)];
    signed char vd = v[base + d];
    __syncthreads();   // all reads done before in-place writes

    float rotq = (d < 64) ? -qp : qp;
    float rotk = (d < 64) ? -kp : kp;
    q[base + d] = quant_i8(qd * cs + rotq * sn);
    k[base + d] = quant_i8(kd * cs + rotk * sn);
    vt[((size_t)((b * NH + h) * HD + d)) * SEQ + s] = vd;
}

// ---------------- attention: QK^T -> softmax -> quant -> PV ----------------
// one block = (b, h, 16-row q tile). LDS: 16x1024 f32 scores (64KB), then
// reused (after barrier) as 16 x 1040-stride int8 P matrix.
__global__ __launch_bounds__(256) void attn_kernel(
    const signed char* __restrict__ q, const signed char* __restrict__ k,
    const signed char* __restrict__ vt, signed char* __restrict__ ctx)
{
    __shared__ __align__(16) char smem[65536];
    float* sc = (float*)smem;
    signed char* p8 = (signed char*)smem;

    const int w    = threadIdx.x >> 6;
    const int lane = threadIdx.x & 63;
    const int bid  = blockIdx.x;
    const int mt   = bid & 63;       // 64 row-tiles of 16
    const int bh   = bid >> 6;       // b*NH + h
    const int b    = bh >> 5, h = bh & 31;
    const int m0   = mt * 16;
    const int lm   = lane & 15;
    const int lkb  = (lane >> 4) * 16;
    const int quad = lane >> 4;

    const float SCALE = 0.0025f / 11.313708498984761f;  // S_Q*S_K/sqrt(HD)

    // ---- phase A: scores (M=16, N=1024, K=128); wave w owns col strip w*256
    const signed char* qbase = q + ((size_t)(b * SEQ + m0 + lm) * NH + h) * (size_t)HD + lkb;
    v4i a0 = *(const v4i*)qbase;
    v4i a1 = *(const v4i*)(qbase + 64);

    #pragma unroll
    for (int j = 0; j < 16; j++) {
        int col = w * 256 + j * 16;
        const signed char* kb = k + ((size_t)(b * SEQ + col + lm) * NH + h) * (size_t)HD + lkb;
        v4i b0 = *(const v4i*)kb;
        v4i b1 = *(const v4i*)(kb + 64);
        v4i acc = {};
        acc = __builtin_amdgcn_mfma_i32_16x16x64_i8(a0, b0, acc, 0, 0, 0);
        acc = __builtin_amdgcn_mfma_i32_16x16x64_i8(a1, b1, acc, 0, 0, 0);
        #pragma unroll
        for (int r = 0; r < 4; r++) {
            int row = quad * 4 + r;
            sc[row * 1024 + col + lm] = (float)acc[r] * SCALE;
        }
    }
    __syncthreads();

    // ---- phase B: softmax; wave w owns rows 4w..4w+3; lane holds 4 chunks of 4
    int packed[4][4];
    #pragma unroll
    for (int r = 0; r < 4; r++) {
        int row = w * 4 + r;
        float vals[16];
        #pragma unroll
        for (int c = 0; c < 4; c++) {
            float4 f = *(const float4*)(sc + row * 1024 + c * 256 + lane * 4);
            vals[c * 4 + 0] = f.x; vals[c * 4 + 1] = f.y;
            vals[c * 4 + 2] = f.z; vals[c * 4 + 3] = f.w;
        }
        float mx = -1e30f;
        #pragma unroll
        for (int t = 0; t < 16; t++) mx = fmaxf(mx, vals[t]);
        #pragma unroll
        for (int off = 32; off >= 1; off >>= 1) mx = fmaxf(mx, __shfl_xor(mx, off));
        float sum = 0.f;
        #pragma unroll
        for (int t = 0; t < 16; t++) { vals[t] = expf(vals[t] - mx); sum += vals[t]; }
        #pragma unroll
        for (int off = 32; off >= 1; off >>= 1) sum += __shfl_xor(sum, off);
        float sf = 127.0f / sum;
        #pragma unroll
        for (int c = 0; c < 4; c++) {
            union { signed char cc[4]; int ii; } u;
            #pragma unroll
            for (int t = 0; t < 4; t++) u.cc[t] = quant_i8(vals[c * 4 + t] * sf);
            packed[r][c] = u.ii;
        }
    }
    __syncthreads();   // all float reads complete before overwriting as int8

    #pragma unroll
    for (int r = 0; r < 4; r++)
        #pragma unroll
        for (int c = 0; c < 4; c++)
            *(int*)(p8 + (w * 4 + r) * 1040 + c * 256 + lane * 4) = packed[r][c];
    __syncthreads();

    // ---- phase D: PV (M=16, N=128, K=1024); wave w owns cols 32w..32w+31
    v4i accp[2] = {};
    for (int kk = 0; kk < SEQ; kk += 64) {
        v4i af = *(const v4i*)(p8 + lm * 1040 + kk + lkb);
        #pragma unroll
        for (int j = 0; j < 2; j++) {
            int col = w * 32 + j * 16;
            const signed char* vb = vt + ((size_t)(bh * HD + col + lm)) * (size_t)SEQ + kk + lkb;
            accp[j] = __builtin_amdgcn_mfma_i32_16x16x64_i8(af, *(const v4i*)vb, accp[j], 0, 0, 0);
        }
    }
    #pragma unroll
    for (int j = 0; j < 2; j++) {
        #pragma unroll
        for (int r = 0; r < 4; r++) {
            int row = quad * 4 + r;
            int col = w * 32 + j * 16 + lm;
            ctx[((size_t)(b * SEQ + m0 + row) * NH + h) * (size_t)HD + col] =
                quant_i8((float)accp[j][r] * (1.0f / 127.0f));
        }
    }
}

// ---------------- launch ----------------
extern "C" void kernel_launch(void* const* d_in, const int* in_sizes, int n_in,
                              void* d_out, int out_size, void* d_ws, size_t ws_size,
                              hipStream_t stream)
{
    const float* hidden = (const float*)d_in[0];
    const int* pos_ids  = (const int*)d_in[1];
    const int* w_q = (const int*)d_in[2];
    const int* w_k = (const int*)d_in[3];
    const int* w_v = (const int*)d_in[4];
    const int* w_o = (const int*)d_in[5];
    const int* b_q = (const int*)d_in[6];
    const int* b_k = (const int*)d_in[7];
    const int* b_v = (const int*)d_in[8];
    const float* b_o = (const float*)d_in[9];
    float* out = (float*)d_out;

    char* ws = (char*)d_ws;
    const size_t WSZ = (size_t)HID * HID;           // 16 MiB per weight
    signed char* wq8 = (signed char*)ws;
    signed char* wk8 = wq8 + WSZ;
    signed char* wv8 = wk8 + WSZ;
    signed char* wo8 = wv8 + WSZ;
    signed char* x8  = wo8 + WSZ;
    const size_t ASZ = (size_t)BB * SEQ * HID;      // 8 MiB per activation
    signed char* q8  = x8 + ASZ;
    signed char* k8  = q8 + ASZ;
    signed char* v8  = k8 + ASZ;
    signed char* vt8 = v8 + ASZ;
    signed char* c8  = vt8 + ASZ;

    int wn4 = HID * HID / 4;
    pack_i8_kernel<<<wn4 / 256, 256, 0, stream>>>(w_q, wq8, wn4);
    pack_i8_kernel<<<wn4 / 256, 256, 0, stream>>>(w_k, wk8, wn4);
    pack_i8_kernel<<<wn4 / 256, 256, 0, stream>>>(w_v, wv8, wn4);
    pack_i8_kernel<<<wn4 / 256, 256, 0, stream>>>(w_o, wo8, wn4);
    int xn4 = (int)(ASZ / 4);
    quant_x_kernel<<<xn4 / 256, 256, 0, stream>>>(hidden, x8, xn4);

    dim3 g(HID / 128, BB * SEQ / 128);  // (32, 16)
    // alpha = S_IN*S_W/S_Q = 0.004, beta = S_B/S_Q = 2.0
    gemm_i8_kernel<false><<<g, 256, 0, stream>>>(x8, wq8, b_q, q8, BB * SEQ, HID, HID, 0.004f, 2.0f);
    gemm_i8_kernel<false><<<g, 256, 0, stream>>>(x8, wk8, b_k, k8, BB * SEQ, HID, HID, 0.004f, 2.0f);
    gemm_i8_kernel<false><<<g, 256, 0, stream>>>(x8, wv8, b_v, v8, BB * SEQ, HID, HID, 0.004f, 2.0f);

    rope_kernel<<<BB * SEQ * NH, 128, 0, stream>>>(pos_ids, q8, k8, v8, vt8);
    attn_kernel<<<BB * NH * (SEQ / 16), 256, 0, stream>>>(q8, k8, vt8, c8);

    // o_proj: fp32 out, scale = S_O*S_W = 5e-4
    gemm_i8_kernel<true><<<g, 256, 0, stream>>>(c8, wo8, b_o, out, BB * SEQ, HID, HID, 0.0005f, 0.0f);
}

// Round 2
// 636.386 us; speedup vs baseline: 1.4763x; 1.4763x over previous
//
#include <hip/hip_runtime.h>
#include <hip/hip_bf16.h>
#include <cstdint>
#include <cstddef>

typedef int v4i __attribute__((ext_vector_type(4)));

#define NH 32
#define HD 128
#define SEQ 1024
#define HID 4096
#define BB 2
#define BKB 128   // K-bytes per LDS tile

__device__ __forceinline__ signed char quant_i8(float x) {
    float r = rintf(x);                       // round-half-to-even, matches jnp.round
    r = fminf(fmaxf(r, -128.0f), 127.0f);
    return (signed char)r;
}

#define GLOAD_LDS16(g, l) \
    __builtin_amdgcn_global_load_lds((const __attribute__((address_space(1))) void*)(g), \
                                     (__attribute__((address_space(3))) void*)(l), 16, 0, 0)

// ---------------- pack int32 -> int8 (all 4 weights in one launch) ----------------
__global__ __launch_bounds__(256) void pack4_i8_kernel(
    const int* __restrict__ s0, const int* __restrict__ s1,
    const int* __restrict__ s2, const int* __restrict__ s3,
    signed char* __restrict__ d0, signed char* __restrict__ d1,
    signed char* __restrict__ d2, signed char* __restrict__ d3, int n4)
{
    int i = blockIdx.x * 256 + threadIdx.x;
    int which = i / n4;
    int idx = i - which * n4;
    const int* src = (which == 0) ? s0 : (which == 1) ? s1 : (which == 2) ? s2 : s3;
    signed char* dst = (which == 0) ? d0 : (which == 1) ? d1 : (which == 2) ? d2 : d3;
    int4 v = ((const int4*)src)[idx];
    char4 c;
    c.x = (signed char)v.x; c.y = (signed char)v.y;
    c.z = (signed char)v.z; c.w = (signed char)v.w;
    ((char4*)dst)[idx] = c;
}

// ---------------- quantize hidden_states ----------------
__global__ __launch_bounds__(256) void quant_x_kernel(const float* __restrict__ src,
                                                      signed char* __restrict__ dst, int n4) {
    int i = blockIdx.x * 256 + threadIdx.x;
    if (i >= n4) return;
    float4 v = ((const float4*)src)[i];
    char4 c;
    c.x = quant_i8(v.x * 50.0f);
    c.y = quant_i8(v.y * 50.0f);
    c.z = quant_i8(v.z * 50.0f);
    c.w = quant_i8(v.w * 50.0f);
    ((char4*)dst)[i] = c;
}

// ---------------- int8 GEMM: C[m,n] = sum_k A[m,k]*B[n,k] ----------------
// 128x128 block tile, BK=128 bytes, LDS-staged via global_load_lds width 16.
// LDS layout XOR-swizzle: chunk kc of row r lives at r*128 + ((kc + (r>>1))&7)*16
// -> fragment ds_read_b128 is conflict-free (2 lanes/bank per 16-lane group).
template<bool F32OUT>
__global__ __launch_bounds__(256) void gemm_i8_lds(
    const signed char* __restrict__ A, const signed char* __restrict__ Bw,
    const void* __restrict__ bias, void* __restrict__ outp,
    int M, int N, int K, float alpha, float beta)
{
    __shared__ __align__(16) signed char sA[128 * BKB];
    __shared__ __align__(16) signed char sB[128 * BKB];

    const int t    = threadIdx.x;
    const int w    = t >> 6;
    const int lane = t & 63;
    const int m0   = blockIdx.y * 128;
    const int n0   = blockIdx.x * 128;
    const int lm   = lane & 15;
    const int quad = lane >> 4;
    const int wm   = (w >> 1) * 64;
    const int wn   = (w & 1) * 64;

    // staging map: slot si = t + 256*p ; row = si>>3, slot_kc = si&7,
    // global chunk kc = (slot_kc - (row>>1)) & 7
    int srow[4], skc[4];
    #pragma unroll
    for (int p = 0; p < 4; p++) {
        int si = t + 256 * p;
        int row = si >> 3;
        srow[p] = row;
        skc[p] = ((si & 7) - (row >> 1)) & 7;
    }

    v4i acc[4][4] = {};

    for (int k0 = 0; k0 < K; k0 += BKB) {
        __syncthreads();   // previous tile's reads complete
        #pragma unroll
        for (int p = 0; p < 4; p++) {
            const signed char* ga = A + (size_t)(m0 + srow[p]) * K + k0 + skc[p] * 16;
            GLOAD_LDS16(ga, sA + t * 16 + p * 4096);
        }
        #pragma unroll
        for (int p = 0; p < 4; p++) {
            const signed char* gb = Bw + (size_t)(n0 + srow[p]) * K + k0 + skc[p] * 16;
            GLOAD_LDS16(gb, sB + t * 16 + p * 4096);
        }
        __syncthreads();   // staging visible (compiler emits vmcnt(0) drain)

        #pragma unroll
        for (int ks = 0; ks < 2; ks++) {
            v4i af[4], bf[4];
            #pragma unroll
            for (int i = 0; i < 4; i++) {
                int row = wm + 16 * i + lm;
                int slot = (ks * 4 + quad + (lm >> 1)) & 7;   // (kc + row>>1)&7, wm/16i drop out mod 8
                af[i] = *(const v4i*)(sA + row * BKB + slot * 16);
            }
            #pragma unroll
            for (int j = 0; j < 4; j++) {
                int row = wn + 16 * j + lm;
                int slot = (ks * 4 + quad + (lm >> 1)) & 7;
                bf[j] = *(const v4i*)(sB + row * BKB + slot * 16);
            }
            #pragma unroll
            for (int i = 0; i < 4; i++)
                #pragma unroll
                for (int j = 0; j < 4; j++)
                    acc[i][j] = __builtin_amdgcn_mfma_i32_16x16x64_i8(af[i], bf[j], acc[i][j], 0, 0, 0);
        }
    }

    const int orow = quad * 4;
    #pragma unroll
    for (int i = 0; i < 4; i++) {
        #pragma unroll
        for (int j = 0; j < 4; j++) {
            #pragma unroll
            for (int r = 0; r < 4; r++) {
                int row = m0 + wm + 16 * i + orow + r;
                int col = n0 + wn + 16 * j + lm;
                float v = (float)acc[i][j][r];
                if (F32OUT) {
                    ((float*)outp)[(size_t)row * N + col] = v * alpha + ((const float*)bias)[col];
                } else {
                    float q = v * alpha + (float)((const int*)bias)[col] * beta;
                    ((signed char*)outp)[(size_t)row * N + col] = quant_i8(q);
                }
            }
        }
    }
}

// ---------------- RoPE (in-place on q,k) + V transpose ----------------
__global__ __launch_bounds__(128) void rope_kernel(
    const int* __restrict__ pos_ids, signed char* __restrict__ q,
    signed char* __restrict__ k, const signed char* __restrict__ v,
    signed char* __restrict__ vt)
{
    int bid = blockIdx.x;
    int h = bid & (NH - 1);
    int s = (bid >> 5) & (SEQ - 1);
    int b = bid >> 15;
    int d = threadIdx.x;
    size_t base = ((size_t)(b * SEQ + s) * NH + h) * (size_t)HD;
    int pos = pos_ids[b * SEQ + s];

    float inv = expf(-(float)(2 * (d & 63)) * (9.210340371976184f / 128.0f));
    float freq = (float)pos * inv;
    float cs = cosf(freq), sn = sinf(freq);

    float qd = (float)q[base + d];
    float qp = (float)q[base + (d ^ 64)];
    float kd = (float)k[base + d];
    float kp = (float)k[base + (d ^ 64)];
    signed char vd = v[base + d];
    __syncthreads();   // all reads done before in-place writes

    float rotq = (d < 64) ? -qp : qp;
    float rotk = (d < 64) ? -kp : kp;
    q[base + d] = quant_i8(qd * cs + rotq * sn);
    k[base + d] = quant_i8(kd * cs + rotk * sn);
    vt[((size_t)((b * NH + h) * HD + d)) * SEQ + s] = vd;
}

// ---------------- attention: QK^T -> softmax -> quant -> PV ----------------
__global__ __launch_bounds__(256) void attn_kernel(
    const signed char* __restrict__ q, const signed char* __restrict__ k,
    const signed char* __restrict__ vt, signed char* __restrict__ ctx)
{
    __shared__ __align__(16) char smem[65536];
    float* sc = (float*)smem;
    signed char* p8 = (signed char*)smem;

    const int w    = threadIdx.x >> 6;
    const int lane = threadIdx.x & 63;
    const int bid  = blockIdx.x;
    const int mt   = bid & 63;
    const int bh   = bid >> 6;
    const int b    = bh >> 5, h = bh & 31;
    const int m0   = mt * 16;
    const int lm   = lane & 15;
    const int lkb  = (lane >> 4) * 16;
    const int quad = lane >> 4;

    const float SCALE = 0.0025f / 11.313708498984761f;  // S_Q*S_K/sqrt(HD)
    const float LOG2E = 1.4426950408889634f;

    // ---- phase A: scores (M=16, N=1024, K=128)
    const signed char* qbase = q + ((size_t)(b * SEQ + m0 + lm) * NH + h) * (size_t)HD + lkb;
    v4i a0 = *(const v4i*)qbase;
    v4i a1 = *(const v4i*)(qbase + 64);

    #pragma unroll
    for (int j = 0; j < 16; j++) {
        int col = w * 256 + j * 16;
        const signed char* kb = k + ((size_t)(b * SEQ + col + lm) * NH + h) * (size_t)HD + lkb;
        v4i b0 = *(const v4i*)kb;
        v4i b1 = *(const v4i*)(kb + 64);
        v4i acc = {};
        acc = __builtin_amdgcn_mfma_i32_16x16x64_i8(a0, b0, acc, 0, 0, 0);
        acc = __builtin_amdgcn_mfma_i32_16x16x64_i8(a1, b1, acc, 0, 0, 0);
        #pragma unroll
        for (int r = 0; r < 4; r++) {
            int row = quad * 4 + r;
            sc[row * 1024 + col + lm] = (float)acc[r] * SCALE;
        }
    }
    __syncthreads();

    // ---- phase B: softmax
    int packed[4][4];
    #pragma unroll
    for (int r = 0; r < 4; r++) {
        int row = w * 4 + r;
        float vals[16];
        #pragma unroll
        for (int c = 0; c < 4; c++) {
            float4 f = *(const float4*)(sc + row * 1024 + c * 256 + lane * 4);
            vals[c * 4 + 0] = f.x; vals[c * 4 + 1] = f.y;
            vals[c * 4 + 2] = f.z; vals[c * 4 + 3] = f.w;
        }
        float mx = -1e30f;
        #pragma unroll
        for (int t = 0; t < 16; t++) mx = fmaxf(mx, vals[t]);
        #pragma unroll
        for (int off = 32; off >= 1; off >>= 1) mx = fmaxf(mx, __shfl_xor(mx, off));
        float sum = 0.f;
        #pragma unroll
        for (int t = 0; t < 16; t++) { vals[t] = exp2f((vals[t] - mx) * LOG2E); sum += vals[t]; }
        #pragma unroll
        for (int off = 32; off >= 1; off >>= 1) sum += __shfl_xor(sum, off);
        float sf = 127.0f / sum;
        #pragma unroll
        for (int c = 0; c < 4; c++) {
            union { signed char cc[4]; int ii; } u;
            #pragma unroll
            for (int t = 0; t < 4; t++) u.cc[t] = quant_i8(vals[c * 4 + t] * sf);
            packed[r][c] = u.ii;
        }
    }
    __syncthreads();

    #pragma unroll
    for (int r = 0; r < 4; r++)
        #pragma unroll
        for (int c = 0; c < 4; c++)
            *(int*)(p8 + (w * 4 + r) * 1040 + c * 256 + lane * 4) = packed[r][c];
    __syncthreads();

    // ---- phase D: PV (M=16, N=128, K=1024)
    v4i accp[2] = {};
    for (int kk = 0; kk < SEQ; kk += 64) {
        v4i af = *(const v4i*)(p8 + lm * 1040 + kk + lkb);
        #pragma unroll
        for (int j = 0; j < 2; j++) {
            int col = w * 32 + j * 16;
            const signed char* vb = vt + ((size_t)(bh * HD + col + lm)) * (size_t)SEQ + kk + lkb;
            accp[j] = __builtin_amdgcn_mfma_i32_16x16x64_i8(af, *(const v4i*)vb, accp[j], 0, 0, 0);
        }
    }
    #pragma unroll
    for (int j = 0; j < 2; j++) {
        #pragma unroll
        for (int r = 0; r < 4; r++) {
            int row = quad * 4 + r;
            int col = w * 32 + j * 16 + lm;
            ctx[((size_t)(b * SEQ + m0 + row) * NH + h) * (size_t)HD + col] =
                quant_i8((float)accp[j][r] * (1.0f / 127.0f));
        }
    }
}

// ---------------- launch ----------------
extern "C" void kernel_launch(void* const* d_in, const int* in_sizes, int n_in,
                              void* d_out, int out_size, void* d_ws, size_t ws_size,
                              hipStream_t stream)
{
    const float* hidden = (const float*)d_in[0];
    const int* pos_ids  = (const int*)d_in[1];
    const int* w_q = (const int*)d_in[2];
    const int* w_k = (const int*)d_in[3];
    const int* w_v = (const int*)d_in[4];
    const int* w_o = (const int*)d_in[5];
    const int* b_q = (const int*)d_in[6];
    const int* b_k = (const int*)d_in[7];
    const int* b_v = (const int*)d_in[8];
    const float* b_o = (const float*)d_in[9];
    float* out = (float*)d_out;

    char* ws = (char*)d_ws;
    const size_t WSZ = (size_t)HID * HID;
    signed char* wq8 = (signed char*)ws;
    signed char* wk8 = wq8 + WSZ;
    signed char* wv8 = wk8 + WSZ;
    signed char* wo8 = wv8 + WSZ;
    signed char* x8  = wo8 + WSZ;
    const size_t ASZ = (size_t)BB * SEQ * HID;
    signed char* q8  = x8 + ASZ;
    signed char* k8  = q8 + ASZ;
    signed char* v8  = k8 + ASZ;
    signed char* vt8 = v8 + ASZ;
    signed char* c8  = vt8 + ASZ;

    int wn4 = HID * HID / 4;
    pack4_i8_kernel<<<4 * wn4 / 256, 256, 0, stream>>>(w_q, w_k, w_v, w_o,
                                                       wq8, wk8, wv8, wo8, wn4);
    int xn4 = (int)(ASZ / 4);
    quant_x_kernel<<<xn4 / 256, 256, 0, stream>>>(hidden, x8, xn4);

    dim3 g(HID / 128, BB * SEQ / 128);  // (32, 16)
    gemm_i8_lds<false><<<g, 256, 0, stream>>>(x8, wq8, b_q, q8, BB * SEQ, HID, HID, 0.004f, 2.0f);
    gemm_i8_lds<false><<<g, 256, 0, stream>>>(x8, wk8, b_k, k8, BB * SEQ, HID, HID, 0.004f, 2.0f);
    gemm_i8_lds<false><<<g, 256, 0, stream>>>(x8, wv8, b_v, v8, BB * SEQ, HID, HID, 0.004f, 2.0f);

    rope_kernel<<<BB * SEQ * NH, 128, 0, stream>>>(pos_ids, q8, k8, v8, vt8);
    attn_kernel<<<BB * NH * (SEQ / 16), 256, 0, stream>>>(q8, k8, vt8, c8);

    gemm_i8_lds<true><<<g, 256, 0, stream>>>(c8, wo8, b_o, out, BB * SEQ, HID, HID, 0.0005f, 0.0f);
}

// Round 3
// 604.755 us; speedup vs baseline: 1.5535x; 1.0523x over previous
//
#include <hip/hip_runtime.h>
#include <hip/hip_bf16.h>
#include <cstdint>
#include <cstddef>

typedef int v4i __attribute__((ext_vector_type(4)));

#define NH 32
#define HD 128
#define SEQ 1024
#define HID 4096
#define BB 2
#define BKB 128   // K-bytes per LDS tile

__device__ __forceinline__ signed char quant_i8(float x) {
    float r = rintf(x);                       // round-half-to-even, matches jnp.round
    r = fminf(fmaxf(r, -128.0f), 127.0f);
    return (signed char)r;
}

#define GLOAD_LDS16(g, l) \
    __builtin_amdgcn_global_load_lds((const __attribute__((address_space(1))) void*)(g), \
                                     (__attribute__((address_space(3))) void*)(l), 16, 0, 0)

// ---------------- pack int32 -> int8 (all 4 weights in one launch) ----------------
__global__ __launch_bounds__(256) void pack4_i8_kernel(
    const int* __restrict__ s0, const int* __restrict__ s1,
    const int* __restrict__ s2, const int* __restrict__ s3,
    signed char* __restrict__ d0, signed char* __restrict__ d1,
    signed char* __restrict__ d2, signed char* __restrict__ d3, int n4)
{
    int i = blockIdx.x * 256 + threadIdx.x;
    int which = i / n4;
    int idx = i - which * n4;
    const int* src = (which == 0) ? s0 : (which == 1) ? s1 : (which == 2) ? s2 : s3;
    signed char* dst = (which == 0) ? d0 : (which == 1) ? d1 : (which == 2) ? d2 : d3;
    int4 v = ((const int4*)src)[idx];
    char4 c;
    c.x = (signed char)v.x; c.y = (signed char)v.y;
    c.z = (signed char)v.z; c.w = (signed char)v.w;
    ((char4*)dst)[idx] = c;
}

// ---------------- quantize hidden_states ----------------
__global__ __launch_bounds__(256) void quant_x_kernel(const float* __restrict__ src,
                                                      signed char* __restrict__ dst, int n4) {
    int i = blockIdx.x * 256 + threadIdx.x;
    if (i >= n4) return;
    float4 v = ((const float4*)src)[i];
    char4 c;
    c.x = quant_i8(v.x * 50.0f);
    c.y = quant_i8(v.y * 50.0f);
    c.z = quant_i8(v.z * 50.0f);
    c.w = quant_i8(v.w * 50.0f);
    ((char4*)dst)[i] = c;
}

// ---------------- int8 GEMM core: C[m,n] = sum_k A[m,k]*B[n,k] ----------------
// TM x 128 block tile, BK=128 bytes, LDS-staged via global_load_lds width 16.
// XOR-swizzled LDS chunk layout -> conflict-free ds_read_b128 fragments.
template<int TM, bool F32OUT>
__device__ __forceinline__ void gemm_core(
    const signed char* __restrict__ A, const signed char* __restrict__ Bw,
    const void* __restrict__ bias, void* __restrict__ outp,
    int m0, int n0, int N, int K, float alpha, float beta)
{
    constexpr int MI = TM / 32;     // m-tiles per wave
    constexpr int PA = TM / 32;     // A-staging glds per thread
    __shared__ __align__(16) signed char sA[TM * BKB];
    __shared__ __align__(16) signed char sB[128 * BKB];

    const int t    = threadIdx.x;
    const int w    = t >> 6;
    const int lane = t & 63;
    const int lm   = lane & 15;
    const int quad = lane >> 4;
    const int wm   = (w >> 1) * (TM / 2);
    const int wn   = (w & 1) * 64;

    int srowA[PA], skcA[PA];
    #pragma unroll
    for (int p = 0; p < PA; p++) {
        int si = t + 256 * p;
        int row = si >> 3;
        srowA[p] = row;
        skcA[p] = ((si & 7) - (row >> 1)) & 7;
    }
    int srowB[4], skcB[4];
    #pragma unroll
    for (int p = 0; p < 4; p++) {
        int si = t + 256 * p;
        int row = si >> 3;
        srowB[p] = row;
        skcB[p] = ((si & 7) - (row >> 1)) & 7;
    }

    v4i acc[MI][4] = {};

    for (int k0 = 0; k0 < K; k0 += BKB) {
        __syncthreads();
        #pragma unroll
        for (int p = 0; p < PA; p++) {
            const signed char* ga = A + (size_t)(m0 + srowA[p]) * K + k0 + skcA[p] * 16;
            GLOAD_LDS16(ga, sA + t * 16 + p * 4096);
        }
        #pragma unroll
        for (int p = 0; p < 4; p++) {
            const signed char* gb = Bw + (size_t)(n0 + srowB[p]) * K + k0 + skcB[p] * 16;
            GLOAD_LDS16(gb, sB + t * 16 + p * 4096);
        }
        __syncthreads();

        #pragma unroll
        for (int ks = 0; ks < 2; ks++) {
            v4i af[MI], bf[4];
            #pragma unroll
            for (int i = 0; i < MI; i++) {
                int row = wm + 16 * i + lm;
                int slot = (ks * 4 + quad + (lm >> 1)) & 7;
                af[i] = *(const v4i*)(sA + row * BKB + slot * 16);
            }
            #pragma unroll
            for (int j = 0; j < 4; j++) {
                int row = wn + 16 * j + lm;
                int slot = (ks * 4 + quad + (lm >> 1)) & 7;
                bf[j] = *(const v4i*)(sB + row * BKB + slot * 16);
            }
            #pragma unroll
            for (int i = 0; i < MI; i++)
                #pragma unroll
                for (int j = 0; j < 4; j++)
                    acc[i][j] = __builtin_amdgcn_mfma_i32_16x16x64_i8(af[i], bf[j], acc[i][j], 0, 0, 0);
        }
    }

    const int orow = quad * 4;
    #pragma unroll
    for (int i = 0; i < MI; i++) {
        #pragma unroll
        for (int j = 0; j < 4; j++) {
            #pragma unroll
            for (int r = 0; r < 4; r++) {
                int row = m0 + wm + 16 * i + orow + r;
                int col = n0 + wn + 16 * j + lm;
                float v = (float)acc[i][j][r];
                if (F32OUT) {
                    ((float*)outp)[(size_t)row * N + col] = v * alpha + ((const float*)bias)[col];
                } else {
                    float q = v * alpha + (float)((const int*)bias)[col] * beta;
                    ((signed char*)outp)[(size_t)row * N + col] = quant_i8(q);
                }
            }
        }
    }
}

// fused Q/K/V projection: one dispatch, 1536 blocks (6 nominal blocks/CU)
__global__ __launch_bounds__(256) void gemm_qkv(
    const signed char* __restrict__ x8,
    const signed char* __restrict__ wq, const signed char* __restrict__ wk,
    const signed char* __restrict__ wv,
    const int* __restrict__ bq, const int* __restrict__ bk, const int* __restrict__ bv,
    signed char* __restrict__ q8, signed char* __restrict__ k8, signed char* __restrict__ v8)
{
    const int nblk = blockIdx.x;          // 0..95
    const int which = nblk >> 5;          // 32 blocks of 128 cols per matrix
    const int n0 = (nblk & 31) * 128;
    const int m0 = blockIdx.y * 128;
    const signed char* Bw = (which == 0) ? wq : (which == 1) ? wk : wv;
    const int* bias = (which == 0) ? bq : (which == 1) ? bk : bv;
    signed char* outp = (which == 0) ? q8 : (which == 1) ? k8 : v8;
    gemm_core<128, false>(x8, Bw, bias, outp, m0, n0, HID, HID, 0.004f, 2.0f);
}

// o-proj: 64x128 tile -> 1024 blocks (4 blocks/CU)
__global__ __launch_bounds__(256) void gemm_o(
    const signed char* __restrict__ c8, const signed char* __restrict__ wo,
    const float* __restrict__ bo, float* __restrict__ outp)
{
    gemm_core<64, true>(c8, wo, bo, outp, blockIdx.y * 64, blockIdx.x * 128,
                        HID, HID, 0.0005f, 0.0f);
}

// ---------------- RoPE (in-place on q,k) + V transpose (8 s-rows/thread) ----------------
__global__ __launch_bounds__(128) void rope_kernel(
    const int* __restrict__ pos_ids, signed char* __restrict__ q,
    signed char* __restrict__ k, const signed char* __restrict__ v,
    signed char* __restrict__ vt)
{
    const int bid = blockIdx.x;
    const int sg = bid & 127;            // s-group of 8
    const int h  = (bid >> 7) & (NH - 1);
    const int b  = bid >> 12;
    const int d  = threadIdx.x;
    const int s0 = sg * 8;
    const int bh = b * NH + h;

    float inv = expf(-(float)(2 * (d & 63)) * (9.210340371976184f / 128.0f));

    float qd[8], qp[8], kd[8], kp[8];
    signed char vd[8];
    int pos[8];
    size_t base[8];
    #pragma unroll
    for (int i = 0; i < 8; i++) {
        int s = s0 + i;
        base[i] = ((size_t)(b * SEQ + s) * NH + h) * (size_t)HD;
        pos[i] = pos_ids[b * SEQ + s];
        qd[i] = (float)q[base[i] + d];
        qp[i] = (float)q[base[i] + (d ^ 64)];
        kd[i] = (float)k[base[i] + d];
        kp[i] = (float)k[base[i] + (d ^ 64)];
        vd[i] = v[base[i] + d];
    }
    __syncthreads();   // all in-place reads complete before writes

    union { signed char c[8]; int2 i2; } vu;
    #pragma unroll
    for (int i = 0; i < 8; i++) {
        float freq = (float)pos[i] * inv;
        float cs = cosf(freq), sn = sinf(freq);
        float rotq = (d < 64) ? -qp[i] : qp[i];
        float rotk = (d < 64) ? -kp[i] : kp[i];
        q[base[i] + d] = quant_i8(qd[i] * cs + rotq * sn);
        k[base[i] + d] = quant_i8(kd[i] * cs + rotk * sn);
        vu.c[i] = vd[i];
    }
    *(int2*)(vt + ((size_t)(bh * HD + d)) * SEQ + s0) = vu.i2;
}

// ---------------- attention: S^T = K.Q^T -> register softmax -> quant -> PV ----------------
// One block = (b,h,16 q-rows). Scores kept in VGPRs (S^T layout: lane col = q-row).
// LDS: 16x1040 int8 P + 256B reduce buffer (~17KB) -> 4 blocks/CU at 128 VGPR.
__global__ __launch_bounds__(256, 4) void attn_kernel(
    const signed char* __restrict__ q, const signed char* __restrict__ k,
    const signed char* __restrict__ vt, signed char* __restrict__ ctx)
{
    __shared__ __align__(16) signed char p8[16 * 1040];
    __shared__ float red[64];

    const int w    = threadIdx.x >> 6;
    const int lane = threadIdx.x & 63;
    const int bid  = blockIdx.x;
    const int mt   = bid & 63;
    const int bh   = bid >> 6;
    const int b    = bh >> 5, h = bh & 31;
    const int m0   = mt * 16;
    const int lm   = lane & 15;
    const int quad = lane >> 4;

    const float SCALE = 0.0025f / 11.313708498984761f;  // S_Q*S_K/sqrt(HD)
    const float LOG2E = 1.4426950408889634f;

    // Q as B-operand: lane holds Q[s = m0+lm][k-chunk quad]
    const signed char* qbase = q + ((size_t)(b * SEQ + m0 + lm) * NH + h) * (size_t)HD + quad * 16;
    v4i qb0 = *(const v4i*)qbase;
    v4i qb1 = *(const v4i*)(qbase + 64);

    // ---- phase A: S^T tiles; wave w covers t in [w*256, w*256+256)
    float vals[16][4];
    #pragma unroll
    for (int j = 0; j < 16; j++) {
        int t0 = w * 256 + j * 16;
        const signed char* kb = k + ((size_t)(b * SEQ + t0 + lm) * NH + h) * (size_t)HD + quad * 16;
        v4i a0 = *(const v4i*)kb;
        v4i a1 = *(const v4i*)(kb + 64);
        v4i acc = {};
        acc = __builtin_amdgcn_mfma_i32_16x16x64_i8(a0, qb0, acc, 0, 0, 0);
        acc = __builtin_amdgcn_mfma_i32_16x16x64_i8(a1, qb1, acc, 0, 0, 0);
        #pragma unroll
        for (int r = 0; r < 4; r++) vals[j][r] = (float)acc[r] * SCALE;
    }

    // ---- phase B: softmax over row s = m0+lm (held by lanes lm, lm+16, lm+32, lm+48)
    float mx = vals[0][0];
    #pragma unroll
    for (int j = 0; j < 16; j++)
        #pragma unroll
        for (int r = 0; r < 4; r++) mx = fmaxf(mx, vals[j][r]);
    mx = fmaxf(mx, __shfl_xor(mx, 16));
    mx = fmaxf(mx, __shfl_xor(mx, 32));
    if (lane < 16) red[w * 16 + lane] = mx;
    __syncthreads();
    mx = fmaxf(fmaxf(red[lm], red[16 + lm]), fmaxf(red[32 + lm], red[48 + lm]));

    float sum = 0.f;
    #pragma unroll
    for (int j = 0; j < 16; j++)
        #pragma unroll
        for (int r = 0; r < 4; r++) {
            vals[j][r] = exp2f((vals[j][r] - mx) * LOG2E);
            sum += vals[j][r];
        }
    sum += __shfl_xor(sum, 16);
    sum += __shfl_xor(sum, 32);
    __syncthreads();   // red reuse
    if (lane < 16) red[w * 16 + lane] = sum;
    __syncthreads();
    sum = (red[lm] + red[16 + lm]) + (red[32 + lm] + red[48 + lm]);
    float sf = 127.0f / sum;

    // ---- phase C: quantize + write P (row s = lm, t-group 16j+4*quad)
    #pragma unroll
    for (int j = 0; j < 16; j++) {
        union { signed char cc[4]; int ii; } u;
        #pragma unroll
        for (int r = 0; r < 4; r++) u.cc[r] = quant_i8(vals[j][r] * sf);
        *(int*)(p8 + lm * 1040 + w * 256 + j * 16 + quad * 4) = u.ii;
    }
    __syncthreads();

    // ---- phase D: PV (M=16, N=128, K=1024); wave w owns d-cols [32w, 32w+32)
    const int lkb = quad * 16;
    v4i accp[2] = {};
    for (int kk = 0; kk < SEQ; kk += 64) {
        v4i af = *(const v4i*)(p8 + lm * 1040 + kk + lkb);
        #pragma unroll
        for (int j = 0; j < 2; j++) {
            int col = w * 32 + j * 16;
            const signed char* vb = vt + ((size_t)(bh * HD + col + lm)) * (size_t)SEQ + kk + lkb;
            accp[j] = __builtin_amdgcn_mfma_i32_16x16x64_i8(af, *(const v4i*)vb, accp[j], 0, 0, 0);
        }
    }
    #pragma unroll
    for (int j = 0; j < 2; j++) {
        #pragma unroll
        for (int r = 0; r < 4; r++) {
            int row = quad * 4 + r;
            int col = w * 32 + j * 16 + lm;
            ctx[((size_t)(b * SEQ + m0 + row) * NH + h) * (size_t)HD + col] =
                quant_i8((float)accp[j][r] * (1.0f / 127.0f));
        }
    }
}

// ---------------- launch ----------------
extern "C" void kernel_launch(void* const* d_in, const int* in_sizes, int n_in,
                              void* d_out, int out_size, void* d_ws, size_t ws_size,
                              hipStream_t stream)
{
    const float* hidden = (const float*)d_in[0];
    const int* pos_ids  = (const int*)d_in[1];
    const int* w_q = (const int*)d_in[2];
    const int* w_k = (const int*)d_in[3];
    const int* w_v = (const int*)d_in[4];
    const int* w_o = (const int*)d_in[5];
    const int* b_q = (const int*)d_in[6];
    const int* b_k = (const int*)d_in[7];
    const int* b_v = (const int*)d_in[8];
    const float* b_o = (const float*)d_in[9];
    float* out = (float*)d_out;

    char* ws = (char*)d_ws;
    const size_t WSZ = (size_t)HID * HID;
    signed char* wq8 = (signed char*)ws;
    signed char* wk8 = wq8 + WSZ;
    signed char* wv8 = wk8 + WSZ;
    signed char* wo8 = wv8 + WSZ;
    signed char* x8  = wo8 + WSZ;
    const size_t ASZ = (size_t)BB * SEQ * HID;
    signed char* q8  = x8 + ASZ;
    signed char* k8  = q8 + ASZ;
    signed char* v8  = k8 + ASZ;
    signed char* vt8 = v8 + ASZ;
    signed char* c8  = vt8 + ASZ;

    int wn4 = HID * HID / 4;
    pack4_i8_kernel<<<4 * wn4 / 256, 256, 0, stream>>>(w_q, w_k, w_v, w_o,
                                                       wq8, wk8, wv8, wo8, wn4);
    int xn4 = (int)(ASZ / 4);
    quant_x_kernel<<<xn4 / 256, 256, 0, stream>>>(hidden, x8, xn4);

    // fused QKV projection
    gemm_qkv<<<dim3(96, 16), 256, 0, stream>>>(x8, wq8, wk8, wv8, b_q, b_k, b_v,
                                               q8, k8, v8);

    rope_kernel<<<BB * NH * (SEQ / 8), 128, 0, stream>>>(pos_ids, q8, k8, v8, vt8);
    attn_kernel<<<BB * NH * (SEQ / 16), 256, 0, stream>>>(q8, k8, vt8, c8);

    gemm_o<<<dim3(32, 32), 256, 0, stream>>>(c8, wo8, b_o, out);
}

// Round 4
// 543.993 us; speedup vs baseline: 1.7270x; 1.1117x over previous
//
#include <hip/hip_runtime.h>
#include <hip/hip_bf16.h>
#include <cstdint>
#include <cstddef>

typedef int v4i __attribute__((ext_vector_type(4)));

#define NH 32
#define HD 128
#define SEQ 1024
#define HID 4096
#define BB 2
#define BKB 128   // K-bytes per LDS tile

__device__ __forceinline__ signed char quant_i8(float x) {
    float r = rintf(x);                       // round-half-to-even, matches jnp.round
    r = fminf(fmaxf(r, -128.0f), 127.0f);
    return (signed char)r;
}

#define GLOAD_LDS16(g, l) \
    __builtin_amdgcn_global_load_lds((const __attribute__((address_space(1))) void*)(g), \
                                     (__attribute__((address_space(3))) void*)(l), 16, 0, 0)

// ---------------- pack int32 -> int8 (all 4 weights in one launch) ----------------
__global__ __launch_bounds__(256) void pack4_i8_kernel(
    const int* __restrict__ s0, const int* __restrict__ s1,
    const int* __restrict__ s2, const int* __restrict__ s3,
    signed char* __restrict__ d0, signed char* __restrict__ d1,
    signed char* __restrict__ d2, signed char* __restrict__ d3, int n4)
{
    int i = blockIdx.x * 256 + threadIdx.x;
    int which = i / n4;
    int idx = i - which * n4;
    const int* src = (which == 0) ? s0 : (which == 1) ? s1 : (which == 2) ? s2 : s3;
    signed char* dst = (which == 0) ? d0 : (which == 1) ? d1 : (which == 2) ? d2 : d3;
    int4 v = ((const int4*)src)[idx];
    char4 c;
    c.x = (signed char)v.x; c.y = (signed char)v.y;
    c.z = (signed char)v.z; c.w = (signed char)v.w;
    ((char4*)dst)[idx] = c;
}

// ---------------- quantize hidden_states ----------------
__global__ __launch_bounds__(256) void quant_x_kernel(const float* __restrict__ src,
                                                      signed char* __restrict__ dst, int n4) {
    int i = blockIdx.x * 256 + threadIdx.x;
    if (i >= n4) return;
    float4 v = ((const float4*)src)[i];
    char4 c;
    c.x = quant_i8(v.x * 50.0f);
    c.y = quant_i8(v.y * 50.0f);
    c.z = quant_i8(v.z * 50.0f);
    c.w = quant_i8(v.w * 50.0f);
    ((char4*)dst)[i] = c;
}

// ---------------- int8 GEMM core (double-buffered LDS): C[m,n] = A.B^T ----------------
// 128x128 block tile, BK=128B, 2x32KB LDS buffers. Stage k0+1 right after the
// barrier, compute k0 -> the vmcnt(0) drain at the next barrier overlaps the
// whole MFMA section instead of being exposed (m97-stall fix; works here
// because i8 has 2x MFMA work per staged byte vs bf16 -> headroom below the
// LDS-BW ceiling).
template<bool F32OUT>
__device__ __forceinline__ void gemm_core_db(
    const signed char* __restrict__ A, const signed char* __restrict__ Bw,
    const void* __restrict__ bias, void* __restrict__ outp,
    int m0, int n0, int N, int K, float alpha, float beta)
{
    __shared__ __align__(16) signed char sA[2 * 128 * BKB];
    __shared__ __align__(16) signed char sB[2 * 128 * BKB];

    const int t    = threadIdx.x;
    const int w    = t >> 6;
    const int lane = t & 63;
    const int lm   = lane & 15;
    const int quad = lane >> 4;
    const int wm   = (w >> 1) * 64;
    const int wn   = (w & 1) * 64;

    // staging map with XOR chunk swizzle: chunk kc of row r -> r*128 + ((kc+(r>>1))&7)*16
    int srow[4], skc[4];
    #pragma unroll
    for (int p = 0; p < 4; p++) {
        int si = t + 256 * p;
        int row = si >> 3;
        srow[p] = row;
        skc[p] = ((si & 7) - (row >> 1)) & 7;
    }

    v4i acc[4][4] = {};

    // prologue: stage buffer 0
    #pragma unroll
    for (int p = 0; p < 4; p++) {
        GLOAD_LDS16(A  + (size_t)(m0 + srow[p]) * K + skc[p] * 16, sA + t * 16 + p * 4096);
        GLOAD_LDS16(Bw + (size_t)(n0 + srow[p]) * K + skc[p] * 16, sB + t * 16 + p * 4096);
    }

    int buf = 0;
    for (int k0 = 0; k0 < K; k0 += BKB) {
        __syncthreads();   // publish buf (vmcnt drain overlapped w/ prev compute)

        if (k0 + BKB < K) {
            int nb = buf ^ 1;
            #pragma unroll
            for (int p = 0; p < 4; p++) {
                GLOAD_LDS16(A  + (size_t)(m0 + srow[p]) * K + k0 + BKB + skc[p] * 16,
                            sA + nb * 16384 + t * 16 + p * 4096);
                GLOAD_LDS16(Bw + (size_t)(n0 + srow[p]) * K + k0 + BKB + skc[p] * 16,
                            sB + nb * 16384 + t * 16 + p * 4096);
            }
        }

        const signed char* pA = sA + buf * 16384;
        const signed char* pB = sB + buf * 16384;
        #pragma unroll
        for (int ks = 0; ks < 2; ks++) {
            v4i af[4], bf[4];
            #pragma unroll
            for (int i = 0; i < 4; i++) {
                int row = wm + 16 * i + lm;
                int slot = (ks * 4 + quad + (lm >> 1)) & 7;
                af[i] = *(const v4i*)(pA + row * BKB + slot * 16);
            }
            #pragma unroll
            for (int j = 0; j < 4; j++) {
                int row = wn + 16 * j + lm;
                int slot = (ks * 4 + quad + (lm >> 1)) & 7;
                bf[j] = *(const v4i*)(pB + row * BKB + slot * 16);
            }
            #pragma unroll
            for (int i = 0; i < 4; i++)
                #pragma unroll
                for (int j = 0; j < 4; j++)
                    acc[i][j] = __builtin_amdgcn_mfma_i32_16x16x64_i8(af[i], bf[j], acc[i][j], 0, 0, 0);
        }
        buf ^= 1;
    }

    const int orow = quad * 4;
    #pragma unroll
    for (int i = 0; i < 4; i++) {
        #pragma unroll
        for (int j = 0; j < 4; j++) {
            #pragma unroll
            for (int r = 0; r < 4; r++) {
                int row = m0 + wm + 16 * i + orow + r;
                int col = n0 + wn + 16 * j + lm;
                float v = (float)acc[i][j][r];
                if (F32OUT) {
                    ((float*)outp)[(size_t)row * N + col] = v * alpha + ((const float*)bias)[col];
                } else {
                    float q = v * alpha + (float)((const int*)bias)[col] * beta;
                    ((signed char*)outp)[(size_t)row * N + col] = quant_i8(q);
                }
            }
        }
    }
}

// fused Q/K/V projection
__global__ __launch_bounds__(256) void gemm_qkv(
    const signed char* __restrict__ x8,
    const signed char* __restrict__ wq, const signed char* __restrict__ wk,
    const signed char* __restrict__ wv,
    const int* __restrict__ bq, const int* __restrict__ bk, const int* __restrict__ bv,
    signed char* __restrict__ q8, signed char* __restrict__ k8, signed char* __restrict__ v8)
{
    const int nblk = blockIdx.x;          // 0..95
    const int which = nblk >> 5;
    const int n0 = (nblk & 31) * 128;
    const int m0 = blockIdx.y * 128;
    const signed char* Bw = (which == 0) ? wq : (which == 1) ? wk : wv;
    const int* bias = (which == 0) ? bq : (which == 1) ? bk : bv;
    signed char* outp = (which == 0) ? q8 : (which == 1) ? k8 : v8;
    gemm_core_db<false>(x8, Bw, bias, outp, m0, n0, HID, HID, 0.004f, 2.0f);
}

// o-proj
__global__ __launch_bounds__(256) void gemm_o(
    const signed char* __restrict__ c8, const signed char* __restrict__ wo,
    const float* __restrict__ bo, float* __restrict__ outp)
{
    gemm_core_db<true>(c8, wo, bo, outp, blockIdx.y * 128, blockIdx.x * 128,
                       HID, HID, 0.0005f, 0.0f);
}

// ---------------- RoPE (in-place on q,k) + V transpose (8 s-rows/thread) ----------------
__global__ __launch_bounds__(128) void rope_kernel(
    const int* __restrict__ pos_ids, signed char* __restrict__ q,
    signed char* __restrict__ k, const signed char* __restrict__ v,
    signed char* __restrict__ vt)
{
    const int bid = blockIdx.x;
    const int sg = bid & 127;
    const int h  = (bid >> 7) & (NH - 1);
    const int b  = bid >> 12;
    const int d  = threadIdx.x;
    const int s0 = sg * 8;
    const int bh = b * NH + h;

    float inv = expf(-(float)(2 * (d & 63)) * (9.210340371976184f / 128.0f));

    float qd[8], qp[8], kd[8], kp[8];
    signed char vd[8];
    int pos[8];
    size_t base[8];
    #pragma unroll
    for (int i = 0; i < 8; i++) {
        int s = s0 + i;
        base[i] = ((size_t)(b * SEQ + s) * NH + h) * (size_t)HD;
        pos[i] = pos_ids[b * SEQ + s];
        qd[i] = (float)q[base[i] + d];
        qp[i] = (float)q[base[i] + (d ^ 64)];
        kd[i] = (float)k[base[i] + d];
        kp[i] = (float)k[base[i] + (d ^ 64)];
        vd[i] = v[base[i] + d];
    }
    __syncthreads();

    union { signed char c[8]; int2 i2; } vu;
    #pragma unroll
    for (int i = 0; i < 8; i++) {
        float freq = (float)pos[i] * inv;
        float cs = cosf(freq), sn = sinf(freq);
        float rotq = (d < 64) ? -qp[i] : qp[i];
        float rotk = (d < 64) ? -kp[i] : kp[i];
        q[base[i] + d] = quant_i8(qd[i] * cs + rotq * sn);
        k[base[i] + d] = quant_i8(kd[i] * cs + rotk * sn);
        vu.c[i] = vd[i];
    }
    *(int2*)(vt + ((size_t)(bh * HD + d)) * SEQ + s0) = vu.i2;
}

// ---------------- attention: 32 q-rows/block, K/V frags reused for 2 row-sets ----------------
__global__ __launch_bounds__(256) void attn_kernel(
    const signed char* __restrict__ q, const signed char* __restrict__ k,
    const signed char* __restrict__ vt, signed char* __restrict__ ctx)
{
    __shared__ __align__(16) signed char p8[32 * 1040];
    __shared__ float red[128];

    const int w    = threadIdx.x >> 6;
    const int lane = threadIdx.x & 63;
    const int bid  = blockIdx.x;
    const int mt   = bid & 31;            // 32 row-tiles of 32
    const int bh   = bid >> 5;
    const int b    = bh >> 5, h = bh & 31;
    const int m0   = mt * 32;
    const int lm   = lane & 15;
    const int quad = lane >> 4;

    const float SCALE = 0.0025f / 11.313708498984761f;  // S_Q*S_K/sqrt(HD)
    const float LOG2E = 1.4426950408889634f;

    // two Q-row groups as B-operands
    const signed char* qb_base = q + ((size_t)(b * SEQ + m0 + lm) * NH + h) * (size_t)HD + quad * 16;
    v4i qb0 = *(const v4i*)qb_base;
    v4i qb1 = *(const v4i*)(qb_base + 64);
    const signed char* qb_base2 = qb_base + (size_t)16 * NH * HD;
    v4i qb2 = *(const v4i*)qb_base2;
    v4i qb3 = *(const v4i*)(qb_base2 + 64);

    // ---- phase A: S^T tiles; each K-frag feeds both row-sets
    float vals0[16][4], vals1[16][4];
    #pragma unroll
    for (int j = 0; j < 16; j++) {
        int t0 = w * 256 + j * 16;
        const signed char* kb = k + ((size_t)(b * SEQ + t0 + lm) * NH + h) * (size_t)HD + quad * 16;
        v4i a0 = *(const v4i*)kb;
        v4i a1 = *(const v4i*)(kb + 64);
        v4i acc0 = {}, acc1 = {};
        acc0 = __builtin_amdgcn_mfma_i32_16x16x64_i8(a0, qb0, acc0, 0, 0, 0);
        acc0 = __builtin_amdgcn_mfma_i32_16x16x64_i8(a1, qb1, acc0, 0, 0, 0);
        acc1 = __builtin_amdgcn_mfma_i32_16x16x64_i8(a0, qb2, acc1, 0, 0, 0);
        acc1 = __builtin_amdgcn_mfma_i32_16x16x64_i8(a1, qb3, acc1, 0, 0, 0);
        #pragma unroll
        for (int r = 0; r < 4; r++) {
            vals0[j][r] = (float)acc0[r] * SCALE;
            vals1[j][r] = (float)acc1[r] * SCALE;
        }
    }

    // ---- phase B: softmax for both row-sets (row q = m0+lm / m0+16+lm)
    float mx0 = vals0[0][0], mx1 = vals1[0][0];
    #pragma unroll
    for (int j = 0; j < 16; j++)
        #pragma unroll
        for (int r = 0; r < 4; r++) {
            mx0 = fmaxf(mx0, vals0[j][r]);
            mx1 = fmaxf(mx1, vals1[j][r]);
        }
    mx0 = fmaxf(mx0, __shfl_xor(mx0, 16)); mx0 = fmaxf(mx0, __shfl_xor(mx0, 32));
    mx1 = fmaxf(mx1, __shfl_xor(mx1, 16)); mx1 = fmaxf(mx1, __shfl_xor(mx1, 32));
    if (lane < 16) { red[w * 16 + lane] = mx0; red[64 + w * 16 + lane] = mx1; }
    __syncthreads();
    mx0 = fmaxf(fmaxf(red[lm], red[16 + lm]), fmaxf(red[32 + lm], red[48 + lm]));
    mx1 = fmaxf(fmaxf(red[64 + lm], red[80 + lm]), fmaxf(red[96 + lm], red[112 + lm]));

    float sum0 = 0.f, sum1 = 0.f;
    #pragma unroll
    for (int j = 0; j < 16; j++)
        #pragma unroll
        for (int r = 0; r < 4; r++) {
            vals0[j][r] = exp2f((vals0[j][r] - mx0) * LOG2E); sum0 += vals0[j][r];
            vals1[j][r] = exp2f((vals1[j][r] - mx1) * LOG2E); sum1 += vals1[j][r];
        }
    sum0 += __shfl_xor(sum0, 16); sum0 += __shfl_xor(sum0, 32);
    sum1 += __shfl_xor(sum1, 16); sum1 += __shfl_xor(sum1, 32);
    __syncthreads();
    if (lane < 16) { red[w * 16 + lane] = sum0; red[64 + w * 16 + lane] = sum1; }
    __syncthreads();
    sum0 = (red[lm] + red[16 + lm]) + (red[32 + lm] + red[48 + lm]);
    sum1 = (red[64 + lm] + red[80 + lm]) + (red[96 + lm] + red[112 + lm]);
    float sf0 = 127.0f / sum0, sf1 = 127.0f / sum1;

    // ---- phase C: quantize + write P rows lm and 16+lm
    #pragma unroll
    for (int j = 0; j < 16; j++) {
        union { signed char cc[4]; int ii; } u0, u1;
        #pragma unroll
        for (int r = 0; r < 4; r++) {
            u0.cc[r] = quant_i8(vals0[j][r] * sf0);
            u1.cc[r] = quant_i8(vals1[j][r] * sf1);
        }
        *(int*)(p8 + lm * 1040 + w * 256 + j * 16 + quad * 4) = u0.ii;
        *(int*)(p8 + (16 + lm) * 1040 + w * 256 + j * 16 + quad * 4) = u1.ii;
    }
    __syncthreads();

    // ---- phase D: PV; each Vt frag feeds both row-sets
    const int lkb = quad * 16;
    v4i accp0[2] = {}, accp1[2] = {};
    for (int kk = 0; kk < SEQ; kk += 64) {
        v4i af0 = *(const v4i*)(p8 + lm * 1040 + kk + lkb);
        v4i af1 = *(const v4i*)(p8 + (16 + lm) * 1040 + kk + lkb);
        #pragma unroll
        for (int j = 0; j < 2; j++) {
            int col = w * 32 + j * 16;
            v4i vb = *(const v4i*)(vt + ((size_t)(bh * HD + col + lm)) * (size_t)SEQ + kk + lkb);
            accp0[j] = __builtin_amdgcn_mfma_i32_16x16x64_i8(af0, vb, accp0[j], 0, 0, 0);
            accp1[j] = __builtin_amdgcn_mfma_i32_16x16x64_i8(af1, vb, accp1[j], 0, 0, 0);
        }
    }
    #pragma unroll
    for (int j = 0; j < 2; j++) {
        #pragma unroll
        for (int r = 0; r < 4; r++) {
            int row = quad * 4 + r;
            int col = w * 32 + j * 16 + lm;
            ctx[((size_t)(b * SEQ + m0 + row) * NH + h) * (size_t)HD + col] =
                quant_i8((float)accp0[j][r] * (1.0f / 127.0f));
            ctx[((size_t)(b * SEQ + m0 + 16 + row) * NH + h) * (size_t)HD + col] =
                quant_i8((float)accp1[j][r] * (1.0f / 127.0f));
        }
    }
}

// ---------------- launch ----------------
extern "C" void kernel_launch(void* const* d_in, const int* in_sizes, int n_in,
                              void* d_out, int out_size, void* d_ws, size_t ws_size,
                              hipStream_t stream)
{
    const float* hidden = (const float*)d_in[0];
    const int* pos_ids  = (const int*)d_in[1];
    const int* w_q = (const int*)d_in[2];
    const int* w_k = (const int*)d_in[3];
    const int* w_v = (const int*)d_in[4];
    const int* w_o = (const int*)d_in[5];
    const int* b_q = (const int*)d_in[6];
    const int* b_k = (const int*)d_in[7];
    const int* b_v = (const int*)d_in[8];
    const float* b_o = (const float*)d_in[9];
    float* out = (float*)d_out;

    char* ws = (char*)d_ws;
    const size_t WSZ = (size_t)HID * HID;
    signed char* wq8 = (signed char*)ws;
    signed char* wk8 = wq8 + WSZ;
    signed char* wv8 = wk8 + WSZ;
    signed char* wo8 = wv8 + WSZ;
    signed char* x8  = wo8 + WSZ;
    const size_t ASZ = (size_t)BB * SEQ * HID;
    signed char* q8  = x8 + ASZ;
    signed char* k8  = q8 + ASZ;
    signed char* v8  = k8 + ASZ;
    signed char* vt8 = v8 + ASZ;
    signed char* c8  = vt8 + ASZ;

    int wn4 = HID * HID / 4;
    pack4_i8_kernel<<<4 * wn4 / 256, 256, 0, stream>>>(w_q, w_k, w_v, w_o,
                                                       wq8, wk8, wv8, wo8, wn4);
    int xn4 = (int)(ASZ / 4);
    quant_x_kernel<<<xn4 / 256, 256, 0, stream>>>(hidden, x8, xn4);

    gemm_qkv<<<dim3(96, 16), 256, 0, stream>>>(x8, wq8, wk8, wv8, b_q, b_k, b_v,
                                               q8, k8, v8);

    rope_kernel<<<BB * NH * (SEQ / 8), 128, 0, stream>>>(pos_ids, q8, k8, v8, vt8);
    attn_kernel<<<BB * NH * (SEQ / 32), 256, 0, stream>>>(q8, k8, vt8, c8);

    gemm_o<<<dim3(32, 16), 256, 0, stream>>>(c8, wo8, b_o, out);
}